// Round 8
// baseline (1189.303 us; speedup 1.0000x reference)
//
#include <hip/hip_runtime.h>
#include <cstddef>

// FAN_39273180955145 — round 18. r17 post-mortem: spill fully eliminated
// (FETCH 3.9MB, WRITE 131MB = pure hg) yet dur ROSE 832->853 -> spill was
// never the bottleneck; r14-r17 all land 832-863 regardless. The real limit:
// lockstep barriers at 2 waves/SIMD (65% idle, VALU 34%, MFMA 10%). Fix:
// software-pipeline with 64-row t-tiles, double-buffered khL/vt in the SAME
// 32KB regions (two 64-row tiles stacked):
//   it: [barrier] -> write kh/v(it) to buf(it&1) -> scores+PV(it-1) from
//       buf((it-1)&1).
// One barrier serves both buf-reuse protection and kh publication; producer
// and consumer MFMA chains share a region -> waves slip, latency hidden.
// Also: ls_tot split into 2 accumulators (halves serial add chain).
// Kept from r17 (clean, VGPR 124): single-chain accums everywhere,
// operand-swapped packed vt stores, packed kh stores, in-loop bq, setprio,
// launch_bounds(512,2). Math identical to r8/r10 (passed, absmax 9.8e-4).

typedef unsigned short u16;
typedef unsigned int u32;
typedef short short8 __attribute__((ext_vector_type(8)));
typedef u32 u32x2 __attribute__((ext_vector_type(2)));
typedef float floatx16 __attribute__((ext_vector_type(16)));

__device__ __forceinline__ float b2f(u16 u){ return __uint_as_float(((u32)u) << 16); }
__device__ __forceinline__ u16 f2b(float f){
  u32 u = __float_as_uint(f);
  return (u16)((u + 0x7fffu + ((u >> 16) & 1u)) >> 16);
}
// flagged input load: f32 ? fp32 : bf16; non-finite -> 0
__device__ __forceinline__ float ldf(const u16* p, size_t i, int f32){
  float v = f32 ? ((const float*)p)[i] : b2f(p[i]);
  return __builtin_isfinite(v) ? v : 0.f;
}
__device__ __forceinline__ u32 pk2(float a, float b){
  return ((u32)f2b(b) << 16) | (u32)f2b(a);
}
// [rows][128 bf16] LDS region, 256B rows, 16B-chunk xor swizzle (2-way max = free)
__device__ __forceinline__ int swz(int row, int ch){ return (row << 8) | ((ch ^ (row & 15)) << 4); }
__device__ __forceinline__ floatx16 fz(){
  floatx16 z;
#pragma unroll
  for (int i = 0; i < 16; ++i) z[i] = 0.f;
  return z;
}
__device__ __forceinline__ floatx16 MF(short8 a, short8 b, floatx16 c){
  return __builtin_amdgcn_mfma_f32_32x32x16_bf16(a, b, c, 0, 0, 0);
}
// C-layout 32x32 tile (by value) -> k-chunk A-fragment via xor-32 exchange (r4-verified).
__device__ __forceinline__ short8 frag_from(floatx16 cv, int half, int q5){
  int r0 = half * 8;
  u32 e01 = pk2(cv[r0 + 0], cv[r0 + 1]);
  u32 e23 = pk2(cv[r0 + 2], cv[r0 + 3]);
  u32 o01 = pk2(cv[r0 + 4], cv[r0 + 5]);
  u32 o23 = pk2(cv[r0 + 6], cv[r0 + 7]);
  u32 s0 = q5 ? e01 : o01;
  u32 s1 = q5 ? e23 : o23;
  u32 r0v = __shfl_xor(s0, 32);
  u32 r1v = __shfl_xor(s1, 32);
  union { u32 u[4]; short8 v; } un;
  un.u[0] = q5 ? r0v : e01;
  un.u[1] = q5 ? r1v : e23;
  un.u[2] = q5 ? o01 : r0v;
  un.u[3] = q5 ? o23 : r1v;
  return un.v;
}

// ---------------- dtype detector (r4-verified) ----------------
__global__ __launch_bounds__(256) void k_detect(const u16* x, int* dflag){
  __shared__ int red[256];
  int t = threadIdx.x, cnt = 0;
  for (int i = t; i < 4096; i += 256){
    u16 v = x[2 * i];
    int e = (v >> 7) & 0xFF;
    if (e == 0xFF || e >= 0x90 || (e > 0 && e <= 0x20)) ++cnt;
  }
  red[t] = cnt;
  __syncthreads();
  for (int off = 128; off > 0; off >>= 1){
    if (t < off) red[t] += red[t + off];
    __syncthreads();
  }
  if (t == 0) dflag[0] = (red[0] > 1000) ? 1 : 0;
}

// ---------------- prep kernels ----------------

// Mrow[r][c] = M'[r,c] (row-major, kh A-operand); vWT[d][e] = vW[e][d]; uv = u'.
__global__ __launch_bounds__(128) void k_prepw(const u16* qW, const u16* kW, const u16* vW,
                                               const u16* qb, u16* Mrow, u16* vWT, float* uv,
                                               const int* dflag){
  int fl = dflag[0];
  int i = blockIdx.x >> 7, f = blockIdx.x & 127, e = threadIdx.x;
  size_t qo = (size_t)(i * 128 + e) * 128;   // qW row e
  size_t ko = (size_t)(i * 128 + f) * 128;   // kW row f
  float m = 0.f;
  for (int d = 0; d < 128; ++d) m += ldf(qW, qo + d, fl) * ldf(kW, ko + d, fl);
  const float RS = 0.08838834764831845f;  // 1/sqrt(128)
  Mrow[(i * 128 + e) * 128 + f] = f2b(m * RS);                // M'[e,f] at [e][f]
  vWT[(i * 128 + f) * 128 + e] = f2b(ldf(vW, qo + f, fl));    // vWT[d][e] = vW[e][d]
  __shared__ float red[128];
  red[e] = ldf(kW, ko + e, fl) * ldf(qb, (size_t)i * 128 + e, fl);
  __syncthreads();
  for (int off = 64; off > 0; off >>= 1){
    if (e < off) red[e] += red[e + off];
    __syncthreads();
  }
  if (e == 0) uv[i * 128 + f] = red[0] * RS;
}

__global__ __launch_bounds__(256) void k_h1t(const u16* h1W, u16* h1WT, const int* dflag){
  int fl = dflag[0];
  __shared__ u16 tile[64][130];
  int k0 = blockIdx.x * 64, tid = threadIdx.x;
#pragma unroll 4
  for (int it = 0; it < 32; ++it){
    int r = it * 2 + (tid >> 7), c = tid & 127;
    tile[r][c] = f2b(ldf(h1W, (size_t)(k0 + r) * 128 + c, fl));
  }
  __syncthreads();
#pragma unroll 4
  for (int it = 0; it < 32; ++it){
    int idx = it * 256 + tid, n = idx >> 6, kk = idx & 63;
    h1WT[(size_t)n * 32896 + k0 + kk] = tile[kk][n];
  }
}

// -------- fused embed + 2 attention layers; h in LDS; one block = one batch --------
// Pipelined: 64-row t-tiles, khL/vt double-buffered (two tiles stacked in the
// same 32KB regions). Iteration it: [barrier] kh/v(it)->buf(it&1), then
// scores+PV(it-1) from buf((it-1)&1). 5 iterations per layer (last = drain).

__global__ __launch_bounds__(512, 2) void k_fan(
    const u16* x, const u16* sW, const u16* sb, const u16* hW, const u16* hbe,
    const u16* Mrow, const float* uv, const u16* vWT, const u16* vb,
    const u16* lng, const u16* lnb,
    u16* hgq, u16* se, int qoff, const int* dflag){
  __shared__ alignas(16) u16 hL[32768];    // h   [256 s][128 f], swz, 64KB
  __shared__ alignas(16) u16 vt[16384];    // vT  [128 d][2 buf x 64 t], swz, 32KB
  __shared__ alignas(16) u16 khL[16384];   // kh  [2 buf x 64 t][128 f], swz, 32KB
  __shared__ float c_all[256];             // c_t, whole layer
  __shared__ float u_lds[128];             // u' for current layer
  int fl = dflag[0];
  int bl = blockIdx.x;
  int b = qoff + bl;
  int tid = threadIdx.x, w = tid >> 6, lane = tid & 63, l31 = lane & 31, q5 = lane >> 5;
  size_t xo = (size_t)b * 272;
  const float LKOFF = -20.72326584f;       // ln(1e-9); off-diag log-kernel value

  // scalar embedding (lanes 0..127)
  if (tid < 128){
    float acc = ldf(sb, tid, fl);
#pragma unroll
    for (int j = 0; j < 16; ++j) acc += ldf(x, xo + j, fl) * ldf(sW, (size_t)j * 128 + tid, fl);
    se[(size_t)b * 128 + tid] = f2b(acc);
  }
  // history embedding -> hL
#pragma unroll
  for (int it = 0; it < 8; ++it){
    int c = it * 512 + tid, s = c >> 4, ch = c & 15;
    float xv = ldf(x, xo + 16 + s, fl);
    short8 r;
#pragma unroll
    for (int j = 0; j < 8; ++j)
      r[j] = (short)f2b(xv * ldf(hW, ch * 8 + j, fl) + ldf(hbe, ch * 8 + j, fl));
    *(short8*)((char*)hL + swz(s, ch)) = r;
  }

  int mtv = w & 3, ntv = w >> 2;           // kh/v unit: f/d subtile (4), t subtile (2)
  int scol = 32 * w + l31;

#pragma unroll 1
  for (int li = 0; li < 2; ++li){
    const u16* Mri  = Mrow + li * 16384;
    const u16* vWTi = vWT + li * 16384;
    if (tid < 128) u_lds[tid] = uv[li * 128 + tid];
    float vbl = ldf(vb, (size_t)li * 128 + 32 * mtv + l31, fl);
    __syncthreads();                 // hL (embed/prev epilogue) + u_lds visible

    float ls_a = 0.f, ls_b = 0.f;
    floatx16 oacc[4];
#pragma unroll
    for (int nt = 0; nt < 4; ++nt) oacc[nt] = fz();

#pragma unroll 1
    for (int it = 0; it < 5; ++it){
      if (it) __syncthreads();       // publishes kh/v(it-1); protects buf reuse
      if (it < 4){
        int t0 = it * 64, buf = it & 1;
        // ---- kh unit: khL[t][f] = sum_e M'[f,e] h[t0+t][e]
        {
          const u16* Ma = Mri + (32 * mtv + l31) * 128 + q5 * 8;
          floatx16 ka = fz();
#pragma unroll 2
          for (int kc = 0; kc < 8; ++kc){
            short8 av = *(const short8*)(Ma + kc * 16);
            short8 bh = *(const short8*)((char*)hL + swz(t0 + 32 * ntv + l31, 2 * kc + q5));
            ka = MF(av, bh, ka);
          }
          int tloc = 64 * buf + 32 * ntv + l31;
#pragma unroll
          for (int qd = 0; qd < 4; ++qd){
            // regs 4qd..4qd+3 -> frow = 32mtv + 8qd + 4q5 + (0..3): one 8B chunk
            u32x2 pv;
            pv.x = pk2(ka[4 * qd + 0], ka[4 * qd + 1]);
            pv.y = pk2(ka[4 * qd + 2], ka[4 * qd + 3]);
            *(u32x2*)((char*)khL + swz(tloc, 4 * mtv + qd) + 8 * q5) = pv;
          }
        }
        // ---- v unit (operand-swapped D[t][d]): vt[d][buf*64 + t]
        {
          const u16* Va = vWTi + (32 * mtv + l31) * 128 + q5 * 8;
          floatx16 va = fz();
#pragma unroll 2
          for (int kc = 0; kc < 8; ++kc){
            short8 avV = *(const short8*)(Va + kc * 16);
            short8 bh  = *(const short8*)((char*)hL + swz(t0 + 32 * ntv + l31, 2 * kc + q5));
            va = MF(bh, avV, va);
          }
#pragma unroll
          for (int qd = 0; qd < 4; ++qd){
            u32x2 pv;
            pv.x = pk2(va[4 * qd + 0] + vbl, va[4 * qd + 1] + vbl);
            pv.y = pk2(va[4 * qd + 2] + vbl, va[4 * qd + 3] + vbl);
            *(u32x2*)((char*)vt + swz(32 * mtv + l31, 8 * buf + 4 * ntv + qd) + 8 * q5) = pv;
          }
        }
        // ---- c_all[t] = u'.h_t (iteration 0 only; consumed from it=1 on)
        if (it == 0){
          int row = 32 * w + l31;
          float dot = 0.f;
#pragma unroll 2
          for (int kc = 0; kc < 8; ++kc){
            int ch = 2 * kc + q5;
            short8 hv = *(const short8*)((char*)hL + swz(row, ch));
#pragma unroll
            for (int j = 0; j < 8; ++j) dot += u_lds[ch * 8 + j] * b2f(hv[j]);
          }
          dot += __shfl_xor(dot, 32);
          if (q5 == 0) c_all[row] = dot;
        }
      }
      if (it > 0){
        int ti = it - 1, buf = ti & 1, t0g = ti * 64;
        // ---- scores + exp + P@V for tile ti (2 mt subtiles of 32 t)
#pragma unroll 1
        for (int mt = 0; mt < 2; ++mt){
          floatx16 sa = fz();
          __builtin_amdgcn_s_setprio(1);
#pragma unroll 2
          for (int kc = 0; kc < 8; ++kc){
            short8 ak = *(const short8*)((char*)khL + swz(64 * buf + 32 * mt + l31, 2 * kc + q5));
            short8 bq = *(const short8*)((char*)hL + swz(32 * w + l31, 2 * kc + q5));
            sa = MF(ak, bq, sa);
          }
          __builtin_amdgcn_s_setprio(0);
#pragma unroll
          for (int reg = 0; reg < 16; ++reg){
            int trl = 32 * mt + (reg & 3) + 8 * (reg >> 2) + 4 * q5;
            int tg = t0g + trl;
            float lk = (tg == scol) ? 0.f : LKOFF;
            float v = sa[reg] + c_all[tg] + lk;
            v = fminf(fmaxf(v, -50.f), 50.f);
            float p = __expf(v - 8.f);   // fixed max: softmax shift-invariant
            sa[reg] = p;
            if (reg & 1) ls_b += p; else ls_a += p;
          }
          // pf frags computed BEFORE the bv loads so sa dies here (register diet)
          short8 pf0 = frag_from(sa, 0, q5);
          short8 pf1 = frag_from(sa, 1, q5);
          __builtin_amdgcn_s_setprio(1);
#pragma unroll
          for (int nt = 0; nt < 4; ++nt){
            short8 bv0 = *(const short8*)((char*)vt + swz(32 * nt + l31, 8 * buf + 2 * (2 * mt + 0) + q5));
            oacc[nt] = MF(pf0, bv0, oacc[nt]);
            short8 bv1 = *(const short8*)((char*)vt + swz(32 * nt + l31, 8 * buf + 2 * (2 * mt + 1) + q5));
            oacc[nt] = MF(pf1, bv1, oacc[nt]);
          }
          __builtin_amdgcn_s_setprio(0);
        }
      }
    }

    // ---- epilogue: /l, +residual, LayerNorm, write back to hL (own rows only)
    // No barrier needed: scores read only own hL rows; epilogue touches own rows.
    float ls_tot = ls_a + ls_b;
    float l_run = ls_tot + __shfl_xor(ls_tot, 32);
    float linv = 1.f / l_run;
    float gv[4], bbv[4];
#pragma unroll
    for (int nt = 0; nt < 4; ++nt){
      gv[nt]  = ldf(lng, (size_t)li * 128 + 32 * nt + l31, fl);
      bbv[nt] = ldf(lnb, (size_t)li * 128 + 32 * nt + l31, fl);
    }
#pragma unroll
    for (int reg = 0; reg < 16; ++reg){
      int rr = (reg & 3) + 8 * (reg >> 2) + 4 * q5;
      int srow = 32 * w + rr;
      float lrv = __shfl(linv, rr);
      float s1 = 0.f, s2 = 0.f;
#pragma unroll
      for (int nt = 0; nt < 4; ++nt){
        int d = 32 * nt + l31;
        float res = b2f(*(const u16*)((char*)hL + swz(srow, d >> 3) + (d & 7) * 2));
        float v = oacc[nt][reg] * lrv + res;
        oacc[nt][reg] = v;
        s1 += v; s2 += v * v;
      }
#pragma unroll
      for (int off = 1; off < 32; off <<= 1){ s1 += __shfl_xor(s1, off); s2 += __shfl_xor(s2, off); }
      float mu = s1 * 0.0078125f;
      float rs = rsqrtf(fmaxf(s2 * 0.0078125f - mu * mu, 0.f) + 1e-5f);
#pragma unroll
      for (int nt = 0; nt < 4; ++nt){
        int d = 32 * nt + l31;
        float v = (oacc[nt][reg] - mu) * rs * gv[nt] + bbv[nt];
        *(u16*)((char*)hL + swz(srow, d >> 3) + (d & 7) * 2) = f2b(v);
      }
    }
    __syncthreads();                   // hL update visible before next layer / store
  }

  // final h -> global, coalesced 16B chunks
#pragma unroll
  for (int it = 0; it < 8; ++it){
    int c = it * 512 + tid, row = c >> 4, ch = c & 15;
    *(short8*)(hgq + (size_t)bl * 32768 + row * 128 + ch * 8) =
        *(const short8*)((char*)hL + swz(row, ch));
  }
}

// ---------------- MLP head ----------------

__global__ __launch_bounds__(256) void k_mlp1(const u16* se, const u16* hgq, const u16* h1WT,
                                              float* part, int qoff, int nb){
  int mb = blockIdx.x, ks = blockIdx.y;
  int tid = threadIdx.x, w = tid >> 6, lane = tid & 63, l31 = lane & 31, q5 = lane >> 5;
  int b0 = mb * 32;
  floatx16 acc = fz();
  const u16* brow = h1WT + (size_t)(32 * w + l31) * 32896;
  int br = b0 + l31;
  const u16* seb = se + (size_t)(qoff + br) * 128;
  const u16* hb = hgq + (size_t)br * 32768;
  for (int kk = 0; kk < 257; ++kk){
    int kbase = ks * 4112 + kk * 16;
    const u16* ap = (kbase < 128) ? (seb + kbase + q5 * 8) : (hb + (kbase - 128) + q5 * 8);
    short8 a = *(const short8*)ap;
    short8 bf = *(const short8*)(brow + kbase + q5 * 8);
    acc = MF(a, bf, acc);
  }
#pragma unroll
  for (int reg = 0; reg < 16; ++reg){
    int rr = (reg & 3) + 8 * (reg >> 2) + 4 * q5;
    part[(size_t)ks * nb * 128 + (size_t)(b0 + rr) * 128 + 32 * w + l31] = acc[reg];
  }
}

__global__ __launch_bounds__(256) void k_mlp1red(const float* part, const u16* h1b, float* z1q,
                                                 const int* dflag, int nb){
  int fl = dflag[0];
  int idx = blockIdx.x * 256 + threadIdx.x;    // 0..nb*128-1
  float s = ldf(h1b, idx & 127, fl);
  size_t stride = (size_t)nb * 128;
#pragma unroll
  for (int ks = 0; ks < 8; ++ks) s += part[(size_t)ks * stride + idx];
  z1q[idx] = fmaxf(s, 0.f);
}

__global__ __launch_bounds__(256) void k_mlp2(const float* z1, const u16* h2W, const u16* h2b,
                                              float* z2, const int* dflag){
  int fl = dflag[0];
  int idx = blockIdx.x * 256 + threadIdx.x;    // 0..131071
  int b = idx >> 6, j = idx & 63;
  float s = ldf(h2b, j, fl);
  const float* zr = z1 + (size_t)b * 128;
  for (int k = 0; k < 128; ++k) s += zr[k] * ldf(h2W, (size_t)k * 64 + j, fl);
  z2[idx] = fmaxf(s, 0.f);
}

__global__ __launch_bounds__(256) void k_mlp3(const float* z2, const u16* h3W, const u16* h3b,
                                              void* out, const int* dflag){
  int fl = dflag[0];
  int b = blockIdx.x * 256 + threadIdx.x;      // 0..2047
  float s = ldf(h3b, 0, fl);
  const float* zr = z2 + (size_t)b * 64;
#pragma unroll
  for (int j = 0; j < 64; ++j) s += zr[j] * ldf(h3W, j, fl);
  if (!__builtin_isfinite(s)) s = 0.f;
  if (fl) ((float*)out)[b] = s;
  else    ((u16*)out)[b] = f2b(s);
}

// ---------------- launch ----------------

extern "C" void kernel_launch(void* const* d_in, const int* in_sizes, int n_in,
                              void* d_out, int out_size, void* d_ws, size_t ws_size,
                              hipStream_t stream) {
  const u16* x   = (const u16*)d_in[0];
  const u16* sW  = (const u16*)d_in[1];
  const u16* sb  = (const u16*)d_in[2];
  const u16* hW  = (const u16*)d_in[3];
  const u16* hb  = (const u16*)d_in[4];
  const u16* qW  = (const u16*)d_in[5];
  const u16* qb  = (const u16*)d_in[6];
  const u16* kW  = (const u16*)d_in[7];
  // d_in[8] = kb : cancels in softmax, unused
  const u16* vW  = (const u16*)d_in[9];
  const u16* vb  = (const u16*)d_in[10];
  const u16* lng = (const u16*)d_in[11];
  const u16* lnb = (const u16*)d_in[12];
  const u16* h1W = (const u16*)d_in[13];
  const u16* h1b = (const u16*)d_in[14];
  const u16* h2W = (const u16*)d_in[15];
  const u16* h2b = (const u16*)d_in[16];
  const u16* h3W = (const u16*)d_in[17];
  const u16* h3b = (const u16*)d_in[18];

  // full-pass mode (r5-r8 ran this branch); quarter mode fallback.
  const int nb = (ws_size >= 153600000ull) ? 2048 : 512;
  const int nq = 2048 / nb;

  char* W = (char*)d_ws;
  size_t o = 0;
  u16*   hg    = (u16*)(W + o); o += (size_t)nb * 65536;   // nb*32768*2
  u16*   h1WT  = (u16*)(W + o); o += 8421376;
  u16*   se    = (u16*)(W + o); o += 524288;               // always full 2048x128 bf16
  u16*   Mrow  = (u16*)(W + o); o += 65536;
  u16*   vWT   = (u16*)(W + o); o += 65536;
  float* uv    = (float*)(W + o); o += 1024;
  float* part  = (float*)(W + o); o += (size_t)nb * 4096;  // 8 * nb*128 * 4B
  float* z1    = (float*)(W + o); o += 1048576;            // always full
  float* z2    = (float*)(W + o); o += 524288;
  int*   dflag = (int*)(W + o);

  k_detect<<<1, 256, 0, stream>>>(x, dflag);
  k_prepw<<<256, 128, 0, stream>>>(qW, kW, vW, qb, Mrow, vWT, uv, dflag);
  k_h1t<<<514, 256, 0, stream>>>(h1W, h1WT, dflag);

  for (int q = 0; q < nq; ++q){
    int qoff = q * nb;
    k_fan<<<nb, 512, 0, stream>>>(x, sW, sb, hW, hb, Mrow, uv, vWT, vb,
                                  lng, lnb, hg, se, qoff, dflag);
    k_mlp1<<<dim3(nb / 32, 8), 256, 0, stream>>>(se, hg, h1WT, part, qoff, nb);
    k_mlp1red<<<nb / 2, 256, 0, stream>>>(part, h1b, z1 + (size_t)qoff * 128, dflag, nb);
  }

  k_mlp2<<<512, 256, 0, stream>>>(z1, h2W, h2b, z2, dflag);
  k_mlp3<<<8, 256, 0, stream>>>(z2, h3W, h3b, d_out, dflag);
}

// Round 9
// 1033.300 us; speedup vs baseline: 1.1510x; 1.1510x over previous
//
#include <hip/hip_runtime.h>
#include <cstddef>

// FAN_39273180955145 — round 19. r18 (pipeline) regressed: producer+consumer
// chains in one region re-spilled (WRITE 347MB) and dur rose to 986. r10-r18
// lesson: barrier-lockstep at 2 waves/SIMD caps at ~830-860us regardless of
// spill. New structure: eliminate kh entirely. S[s,t] = h_s.M'.h_t -> compute
// qh_s = h_s.M' ONCE per layer into registers: MF(A=MrowT rows, B=own-h rows)
// yields D[e][s] with lane = s (own score col); frag_from (A/B frag layouts
// are symmetric) converts it to 8 short8 B-frags (32 VGPRs). Then:
//  * khL deleted; scores = MF(h_t rows from hL, qhf[kc]) - no LDS round trip.
//  * vt -> [128 d][256 t] (64KB, swz2 for 512B rows): whole-layer v staged in
//    one producer phase.
//  * layer = {qh + c_all + v} -> barrier -> 8x{scores+softmax+PV} (NO internal
//    barriers) -> barrier -> epilogue. 3 barriers/layer vs 6; consumer is one
//    long wave-independent region (128 MFMA + softmax) -> waves slip.
//  * accum peak stays r17-clean: producer 16, consumer oacc64+sa16=80.
// k_prepw writes MrowT[e][f] = M'[f,e] (coalesced). Math identical to r8-r17
// (one bf16 rounding of the bilinear intermediate, now on the s-side).

typedef unsigned short u16;
typedef unsigned int u32;
typedef short short8 __attribute__((ext_vector_type(8)));
typedef u32 u32x2 __attribute__((ext_vector_type(2)));
typedef float floatx16 __attribute__((ext_vector_type(16)));

__device__ __forceinline__ float b2f(u16 u){ return __uint_as_float(((u32)u) << 16); }
__device__ __forceinline__ u16 f2b(float f){
  u32 u = __float_as_uint(f);
  return (u16)((u + 0x7fffu + ((u >> 16) & 1u)) >> 16);
}
// flagged input load: f32 ? fp32 : bf16; non-finite -> 0
__device__ __forceinline__ float ldf(const u16* p, size_t i, int f32){
  float v = f32 ? ((const float*)p)[i] : b2f(p[i]);
  return __builtin_isfinite(v) ? v : 0.f;
}
__device__ __forceinline__ u32 pk2(float a, float b){
  return ((u32)f2b(b) << 16) | (u32)f2b(a);
}
// [rows][128 bf16] region, 256B rows, 16B-chunk xor swizzle (8 groups spread = free)
__device__ __forceinline__ int swz(int row, int ch){ return (row << 8) | ((ch ^ (row & 15)) << 4); }
// [rows][256 bf16] region, 512B rows, 32 chunks; xor low4 only (bijective, group-spread)
__device__ __forceinline__ int swz2(int row, int ch){ return (row << 9) | ((ch ^ (row & 15)) << 4); }
__device__ __forceinline__ floatx16 fz(){
  floatx16 z;
#pragma unroll
  for (int i = 0; i < 16; ++i) z[i] = 0.f;
  return z;
}
__device__ __forceinline__ floatx16 MF(short8 a, short8 b, floatx16 c){
  return __builtin_amdgcn_mfma_f32_32x32x16_bf16(a, b, c, 0, 0, 0);
}
// C-layout 32x32 tile (by value) -> k-chunk fragment via xor-32 exchange
// (r4-verified). Element j = tile row 16*half + 8*q5 + j at this lane's col.
// A- and B-fragments share the per-lane shape (own index + 8 k), so the
// result serves as either operand.
__device__ __forceinline__ short8 frag_from(floatx16 cv, int half, int q5){
  int r0 = half * 8;
  u32 e01 = pk2(cv[r0 + 0], cv[r0 + 1]);
  u32 e23 = pk2(cv[r0 + 2], cv[r0 + 3]);
  u32 o01 = pk2(cv[r0 + 4], cv[r0 + 5]);
  u32 o23 = pk2(cv[r0 + 6], cv[r0 + 7]);
  u32 s0 = q5 ? e01 : o01;
  u32 s1 = q5 ? e23 : o23;
  u32 r0v = __shfl_xor(s0, 32);
  u32 r1v = __shfl_xor(s1, 32);
  union { u32 u[4]; short8 v; } un;
  un.u[0] = q5 ? r0v : e01;
  un.u[1] = q5 ? r1v : e23;
  un.u[2] = q5 ? o01 : r0v;
  un.u[3] = q5 ? o23 : r1v;
  return un.v;
}

// ---------------- dtype detector (r4-verified) ----------------
__global__ __launch_bounds__(256) void k_detect(const u16* x, int* dflag){
  __shared__ int red[256];
  int t = threadIdx.x, cnt = 0;
  for (int i = t; i < 4096; i += 256){
    u16 v = x[2 * i];
    int e = (v >> 7) & 0xFF;
    if (e == 0xFF || e >= 0x90 || (e > 0 && e <= 0x20)) ++cnt;
  }
  red[t] = cnt;
  __syncthreads();
  for (int off = 128; off > 0; off >>= 1){
    if (t < off) red[t] += red[t + off];
    __syncthreads();
  }
  if (t == 0) dflag[0] = (red[0] > 1000) ? 1 : 0;
}

// ---------------- prep kernels ----------------

// MrowT[a][b] = M'[b,a] (so A-frag row a = e-output, k = f); vWT[d][e] = vW[e][d]; uv = u'.
__global__ __launch_bounds__(128) void k_prepw(const u16* qW, const u16* kW, const u16* vW,
                                               const u16* qb, u16* MrT, u16* vWT, float* uv,
                                               const int* dflag){
  int fl = dflag[0];
  int i = blockIdx.x >> 7, f = blockIdx.x & 127, e = threadIdx.x;
  size_t qo = (size_t)(i * 128 + e) * 128;   // qW row e
  size_t ko = (size_t)(i * 128 + f) * 128;   // kW row f
  float m = 0.f;
  for (int d = 0; d < 128; ++d) m += ldf(qW, qo + d, fl) * ldf(kW, ko + d, fl);
  const float RS = 0.08838834764831845f;  // 1/sqrt(128)
  // m = M'[e,f]; MrowT[f][e] = M'[e,f]  (coalesced: e = threadIdx)
  MrT[(i * 128 + f) * 128 + e] = f2b(m * RS);
  vWT[(i * 128 + f) * 128 + e] = f2b(ldf(vW, qo + f, fl));    // vWT[d][e] = vW[e][d]
  __shared__ float red[128];
  red[e] = ldf(kW, ko + e, fl) * ldf(qb, (size_t)i * 128 + e, fl);
  __syncthreads();
  for (int off = 64; off > 0; off >>= 1){
    if (e < off) red[e] += red[e + off];
    __syncthreads();
  }
  if (e == 0) uv[i * 128 + f] = red[0] * RS;
}

__global__ __launch_bounds__(256) void k_h1t(const u16* h1W, u16* h1WT, const int* dflag){
  int fl = dflag[0];
  __shared__ u16 tile[64][130];
  int k0 = blockIdx.x * 64, tid = threadIdx.x;
#pragma unroll 4
  for (int it = 0; it < 32; ++it){
    int r = it * 2 + (tid >> 7), c = tid & 127;
    tile[r][c] = f2b(ldf(h1W, (size_t)(k0 + r) * 128 + c, fl));
  }
  __syncthreads();
#pragma unroll 4
  for (int it = 0; it < 32; ++it){
    int idx = it * 256 + tid, n = idx >> 6, kk = idx & 63;
    h1WT[(size_t)n * 32896 + k0 + kk] = tile[kk][n];
  }
}

// -------- fused embed + 2 attention layers; h in LDS; one block = one batch --------

__global__ __launch_bounds__(512, 2) void k_fan(
    const u16* x, const u16* sW, const u16* sb, const u16* hW, const u16* hbe,
    const u16* MrT, const float* uv, const u16* vWT, const u16* vb,
    const u16* lng, const u16* lnb,
    u16* hgq, u16* se, int qoff, const int* dflag){
  __shared__ alignas(16) u16 hL[32768];    // h   [256 s][128 f], swz,  64KB
  __shared__ alignas(16) u16 vt[32768];    // vT  [128 d][256 t], swz2, 64KB
  __shared__ float c_all[256];             // c_t, whole layer
  __shared__ float u_lds[128];             // u' for current layer
  int fl = dflag[0];
  int bl = blockIdx.x;
  int b = qoff + bl;
  int tid = threadIdx.x, w = tid >> 6, lane = tid & 63, l31 = lane & 31, q5 = lane >> 5;
  size_t xo = (size_t)b * 272;
  const float LKOFF = -20.72326584f;       // ln(1e-9); off-diag log-kernel value

  // scalar embedding (lanes 0..127)
  if (tid < 128){
    float acc = ldf(sb, tid, fl);
#pragma unroll
    for (int j = 0; j < 16; ++j) acc += ldf(x, xo + j, fl) * ldf(sW, (size_t)j * 128 + tid, fl);
    se[(size_t)b * 128 + tid] = f2b(acc);
  }
  // history embedding -> hL
#pragma unroll
  for (int it = 0; it < 8; ++it){
    int c = it * 512 + tid, s = c >> 4, ch = c & 15;
    float xv = ldf(x, xo + 16 + s, fl);
    short8 r;
#pragma unroll
    for (int j = 0; j < 8; ++j)
      r[j] = (short)f2b(xv * ldf(hW, ch * 8 + j, fl) + ldf(hbe, ch * 8 + j, fl));
    *(short8*)((char*)hL + swz(s, ch)) = r;
  }

  int mtv = w & 3;                         // d-chunk for v producer
  int scol = 32 * w + l31;

#pragma unroll 1
  for (int li = 0; li < 2; ++li){
    const u16* Ta   = MrT + li * 16384;
    const u16* vWTi = vWT + li * 16384;
    if (tid < 128) u_lds[tid] = uv[li * 128 + tid];
    float vbl = ldf(vb, (size_t)li * 128 + 32 * mtv + l31, fl);
    __syncthreads();                 // hL (embed/prev epilogue) + u_lds visible

    // ---- qh_s = h_s.M' into registers: D[e][s] tiles, lane = col = s = scol.
    // A = MrowT rows (lane = e-row), B = own h row (lane = s-col).
    short8 qhf[8];
#pragma unroll
    for (int et = 0; et < 4; ++et){
      floatx16 qa = fz();
#pragma unroll 2
      for (int kc = 0; kc < 8; ++kc){
        short8 av = *(const short8*)(Ta + (32 * et + l31) * 128 + kc * 16 + q5 * 8);
        short8 bq = *(const short8*)((char*)hL + swz(32 * w + l31, 2 * kc + q5));
        qa = MF(av, bq, qa);
      }
      qhf[2 * et + 0] = frag_from(qa, 0, q5);   // e = 32et + 0..15
      qhf[2 * et + 1] = frag_from(qa, 1, q5);   // e = 32et + 16..31
    }

    // ---- c_all[t] = u'.h_t for all 256 rows
    {
      int row = 32 * w + l31;
      float dot = 0.f;
#pragma unroll 2
      for (int kc = 0; kc < 8; ++kc){
        int ch = 2 * kc + q5;
        short8 hv = *(const short8*)((char*)hL + swz(row, ch));
#pragma unroll
        for (int j = 0; j < 8; ++j) dot += u_lds[ch * 8 + j] * b2f(hv[j]);
      }
      dot += __shfl_xor(dot, 32);
      if (q5 == 0) c_all[row] = dot;
    }

    // ---- v producer: whole layer. vt[d][t] = sum_e h[t,e] vW[e,d] + vb[d].
    // 32 units (4 d-chunks x 8 t-chunks); wave does d=mtv, t-chunks (w>>2)*4+u.
    {
      const u16* Va = vWTi + (32 * mtv + l31) * 128 + q5 * 8;
#pragma unroll 1
      for (int u = 0; u < 4; ++u){
        int tc = (w >> 2) * 4 + u;
        floatx16 va = fz();
#pragma unroll 2
        for (int kc = 0; kc < 8; ++kc){
          short8 avV = *(const short8*)(Va + kc * 16);
          short8 bh  = *(const short8*)((char*)hL + swz(32 * tc + l31, 2 * kc + q5));
          va = MF(bh, avV, va);
        }
        // D[t][d]: lane = d-col, regs = t; 4 consecutive t -> one 8B chunk
#pragma unroll
        for (int qd = 0; qd < 4; ++qd){
          u32x2 pv;
          pv.x = pk2(va[4 * qd + 0] + vbl, va[4 * qd + 1] + vbl);
          pv.y = pk2(va[4 * qd + 2] + vbl, va[4 * qd + 3] + vbl);
          *(u32x2*)((char*)vt + swz2(32 * mtv + l31, 4 * tc + qd) + 8 * q5) = pv;
        }
      }
    }
    __syncthreads();               // vt + c_all complete

    float ls_a = 0.f, ls_b = 0.f;
    floatx16 oacc[4];
#pragma unroll
    for (int nt = 0; nt < 4; ++nt) oacc[nt] = fz();

    // ---- consumer: scores + exp + P@V over 8 t-subtiles; NO internal barriers
#pragma unroll 1
    for (int mt = 0; mt < 8; ++mt){
      floatx16 sa = fz();
      __builtin_amdgcn_s_setprio(1);
#pragma unroll
      for (int kc = 0; kc < 8; ++kc){
        short8 ah = *(const short8*)((char*)hL + swz(32 * mt + l31, 2 * kc + q5));
        sa = MF(ah, qhf[kc], sa);
      }
      __builtin_amdgcn_s_setprio(0);
#pragma unroll
      for (int reg = 0; reg < 16; ++reg){
        int tg = 32 * mt + (reg & 3) + 8 * (reg >> 2) + 4 * q5;
        float lk = (tg == scol) ? 0.f : LKOFF;
        float v = sa[reg] + c_all[tg] + lk;
        v = fminf(fmaxf(v, -50.f), 50.f);
        float p = __expf(v - 8.f);   // fixed max: softmax shift-invariant
        sa[reg] = p;
        if (reg & 1) ls_b += p; else ls_a += p;
      }
      // pf frags computed BEFORE the bv loads so sa dies here (register diet)
      short8 pf0 = frag_from(sa, 0, q5);
      short8 pf1 = frag_from(sa, 1, q5);
      __builtin_amdgcn_s_setprio(1);
#pragma unroll
      for (int nt = 0; nt < 4; ++nt){
        short8 bv0 = *(const short8*)((char*)vt + swz2(32 * nt + l31, 4 * mt + 0 + q5));
        oacc[nt] = MF(pf0, bv0, oacc[nt]);
        short8 bv1 = *(const short8*)((char*)vt + swz2(32 * nt + l31, 4 * mt + 2 + q5));
        oacc[nt] = MF(pf1, bv1, oacc[nt]);
      }
      __builtin_amdgcn_s_setprio(0);
    }
    __syncthreads();                   // all hL reads done before epilogue writes

    // ---- epilogue: /l, +residual, LayerNorm, write back to hL (own rows only)
    float ls_tot = ls_a + ls_b;
    float l_run = ls_tot + __shfl_xor(ls_tot, 32);
    float linv = 1.f / l_run;
    float gv[4], bbv[4];
#pragma unroll
    for (int nt = 0; nt < 4; ++nt){
      gv[nt]  = ldf(lng, (size_t)li * 128 + 32 * nt + l31, fl);
      bbv[nt] = ldf(lnb, (size_t)li * 128 + 32 * nt + l31, fl);
    }
#pragma unroll
    for (int reg = 0; reg < 16; ++reg){
      int rr = (reg & 3) + 8 * (reg >> 2) + 4 * q5;
      int srow = 32 * w + rr;
      float lrv = __shfl(linv, rr);
      float s1 = 0.f, s2 = 0.f;
#pragma unroll
      for (int nt = 0; nt < 4; ++nt){
        int d = 32 * nt + l31;
        float res = b2f(*(const u16*)((char*)hL + swz(srow, d >> 3) + (d & 7) * 2));
        float v = oacc[nt][reg] * lrv + res;
        oacc[nt][reg] = v;
        s1 += v; s2 += v * v;
      }
#pragma unroll
      for (int off = 1; off < 32; off <<= 1){ s1 += __shfl_xor(s1, off); s2 += __shfl_xor(s2, off); }
      float mu = s1 * 0.0078125f;
      float rs = rsqrtf(fmaxf(s2 * 0.0078125f - mu * mu, 0.f) + 1e-5f);
#pragma unroll
      for (int nt = 0; nt < 4; ++nt){
        int d = 32 * nt + l31;
        float v = (oacc[nt][reg] - mu) * rs * gv[nt] + bbv[nt];
        *(u16*)((char*)hL + swz(srow, d >> 3) + (d & 7) * 2) = f2b(v);
      }
    }
    __syncthreads();                   // hL update visible before next layer / store
  }

  // final h -> global, coalesced 16B chunks
#pragma unroll
  for (int it = 0; it < 8; ++it){
    int c = it * 512 + tid, row = c >> 4, ch = c & 15;
    *(short8*)(hgq + (size_t)bl * 32768 + row * 128 + ch * 8) =
        *(const short8*)((char*)hL + swz(row, ch));
  }
}

// ---------------- MLP head ----------------

__global__ __launch_bounds__(256) void k_mlp1(const u16* se, const u16* hgq, const u16* h1WT,
                                              float* part, int qoff, int nb){
  int mb = blockIdx.x, ks = blockIdx.y;
  int tid = threadIdx.x, w = tid >> 6, lane = tid & 63, l31 = lane & 31, q5 = lane >> 5;
  int b0 = mb * 32;
  floatx16 acc = fz();
  const u16* brow = h1WT + (size_t)(32 * w + l31) * 32896;
  int br = b0 + l31;
  const u16* seb = se + (size_t)(qoff + br) * 128;
  const u16* hb = hgq + (size_t)br * 32768;
  for (int kk = 0; kk < 257; ++kk){
    int kbase = ks * 4112 + kk * 16;
    const u16* ap = (kbase < 128) ? (seb + kbase + q5 * 8) : (hb + (kbase - 128) + q5 * 8);
    short8 a = *(const short8*)ap;
    short8 bf = *(const short8*)(brow + kbase + q5 * 8);
    acc = MF(a, bf, acc);
  }
#pragma unroll
  for (int reg = 0; reg < 16; ++reg){
    int rr = (reg & 3) + 8 * (reg >> 2) + 4 * q5;
    part[(size_t)ks * nb * 128 + (size_t)(b0 + rr) * 128 + 32 * w + l31] = acc[reg];
  }
}

__global__ __launch_bounds__(256) void k_mlp1red(const float* part, const u16* h1b, float* z1q,
                                                 const int* dflag, int nb){
  int fl = dflag[0];
  int idx = blockIdx.x * 256 + threadIdx.x;    // 0..nb*128-1
  float s = ldf(h1b, idx & 127, fl);
  size_t stride = (size_t)nb * 128;
#pragma unroll
  for (int ks = 0; ks < 8; ++ks) s += part[(size_t)ks * stride + idx];
  z1q[idx] = fmaxf(s, 0.f);
}

__global__ __launch_bounds__(256) void k_mlp2(const float* z1, const u16* h2W, const u16* h2b,
                                              float* z2, const int* dflag){
  int fl = dflag[0];
  int idx = blockIdx.x * 256 + threadIdx.x;    // 0..131071
  int b = idx >> 6, j = idx & 63;
  float s = ldf(h2b, j, fl);
  const float* zr = z1 + (size_t)b * 128;
  for (int k = 0; k < 128; ++k) s += zr[k] * ldf(h2W, (size_t)k * 64 + j, fl);
  z2[idx] = fmaxf(s, 0.f);
}

__global__ __launch_bounds__(256) void k_mlp3(const float* z2, const u16* h3W, const u16* h3b,
                                              void* out, const int* dflag){
  int fl = dflag[0];
  int b = blockIdx.x * 256 + threadIdx.x;      // 0..2047
  float s = ldf(h3b, 0, fl);
  const float* zr = z2 + (size_t)b * 64;
#pragma unroll
  for (int j = 0; j < 64; ++j) s += zr[j] * ldf(h3W, j, fl);
  if (!__builtin_isfinite(s)) s = 0.f;
  if (fl) ((float*)out)[b] = s;
  else    ((u16*)out)[b] = f2b(s);
}

// ---------------- launch ----------------

extern "C" void kernel_launch(void* const* d_in, const int* in_sizes, int n_in,
                              void* d_out, int out_size, void* d_ws, size_t ws_size,
                              hipStream_t stream) {
  const u16* x   = (const u16*)d_in[0];
  const u16* sW  = (const u16*)d_in[1];
  const u16* sb  = (const u16*)d_in[2];
  const u16* hW  = (const u16*)d_in[3];
  const u16* hb  = (const u16*)d_in[4];
  const u16* qW  = (const u16*)d_in[5];
  const u16* qb  = (const u16*)d_in[6];
  const u16* kW  = (const u16*)d_in[7];
  // d_in[8] = kb : cancels in softmax, unused
  const u16* vW  = (const u16*)d_in[9];
  const u16* vb  = (const u16*)d_in[10];
  const u16* lng = (const u16*)d_in[11];
  const u16* lnb = (const u16*)d_in[12];
  const u16* h1W = (const u16*)d_in[13];
  const u16* h1b = (const u16*)d_in[14];
  const u16* h2W = (const u16*)d_in[15];
  const u16* h2b = (const u16*)d_in[16];
  const u16* h3W = (const u16*)d_in[17];
  const u16* h3b = (const u16*)d_in[18];

  // full-pass mode (r5-r8 ran this branch); quarter mode fallback.
  const int nb = (ws_size >= 153600000ull) ? 2048 : 512;
  const int nq = 2048 / nb;

  char* W = (char*)d_ws;
  size_t o = 0;
  u16*   hg    = (u16*)(W + o); o += (size_t)nb * 65536;   // nb*32768*2
  u16*   h1WT  = (u16*)(W + o); o += 8421376;
  u16*   se    = (u16*)(W + o); o += 524288;               // always full 2048x128 bf16
  u16*   MrT   = (u16*)(W + o); o += 65536;
  u16*   vWT   = (u16*)(W + o); o += 65536;
  float* uv    = (float*)(W + o); o += 1024;
  float* part  = (float*)(W + o); o += (size_t)nb * 4096;  // 8 * nb*128 * 4B
  float* z1    = (float*)(W + o); o += 1048576;            // always full
  float* z2    = (float*)(W + o); o += 524288;
  int*   dflag = (int*)(W + o);

  k_detect<<<1, 256, 0, stream>>>(x, dflag);
  k_prepw<<<256, 128, 0, stream>>>(qW, kW, vW, qb, MrT, vWT, uv, dflag);
  k_h1t<<<514, 256, 0, stream>>>(h1W, h1WT, dflag);

  for (int q = 0; q < nq; ++q){
    int qoff = q * nb;
    k_fan<<<nb, 512, 0, stream>>>(x, sW, sb, hW, hb, MrT, uv, vWT, vb,
                                  lng, lnb, hg, se, qoff, dflag);
    k_mlp1<<<dim3(nb / 32, 8), 256, 0, stream>>>(se, hg, h1WT, part, qoff, nb);
    k_mlp1red<<<nb / 2, 256, 0, stream>>>(part, h1b, z1 + (size_t)qoff * 128, dflag, nb);
  }

  k_mlp2<<<512, 256, 0, stream>>>(z1, h2W, h2b, z2, dflag);
  k_mlp3<<<8, 256, 0, stream>>>(z2, h3W, h3b, d_out, dflag);
}

// Round 11
// 1021.207 us; speedup vs baseline: 1.1646x; 1.0118x over previous
//
#include <hip/hip_runtime.h>
#include <hip/hip_bf16.h>
#include <cstddef>

// FAN_39273180955145 — round 21. r20 failed (absmax 0.114): the
// v_permlane32_swap_b32 frag_from rewrite used unverified swap semantics.
// r21 reverts ONLY the lane-exchange to the r4-verified __shfl_xor(,32)
// path; keeps r20's safe wins:
//  * pk2/f2b via __float22bfloat162_rn/__float2bfloat16 (v_cvt_pk_bf16_f32,
//    1 op per pair, bit-identical RNE to the old manual rounding).
//  * softmax folding: c_all stores c+LKOFF-8; per-elem add, diag-fix,
//    clamp[-58,42], exp; c reads as f32x4 (aligned, rows consecutive).
//  * cvt_pk packing in embed, v-producer, kh-free structure (r19):
//    qh in regs, vt[128][256] whole-layer, 3 barriers/layer.
// Structure/math otherwise identical to r19 (passed, 9.8e-4).

typedef unsigned short u16;
typedef unsigned int u32;
typedef short short8 __attribute__((ext_vector_type(8)));
typedef u32 u32x2 __attribute__((ext_vector_type(2)));
typedef float floatx16 __attribute__((ext_vector_type(16)));
typedef float f32x4 __attribute__((ext_vector_type(4)));

__device__ __forceinline__ float b2f(u16 u){ return __uint_as_float(((u32)u) << 16); }
__device__ __forceinline__ u16 f2b(float f){
  __hip_bfloat16 h = __float2bfloat16(f);          // RNE, = old manual round
  return *reinterpret_cast<u16*>(&h);
}
__device__ __forceinline__ u32 pk2(float a, float b){
  float2 t; t.x = a; t.y = b;
  __hip_bfloat162 h = __float22bfloat162_rn(t);    // v_cvt_pk_bf16_f32 (lo=a)
  return *reinterpret_cast<u32*>(&h);
}
// flagged input load: f32 ? fp32 : bf16; non-finite -> 0
__device__ __forceinline__ float ldf(const u16* p, size_t i, int f32){
  float v = f32 ? ((const float*)p)[i] : b2f(p[i]);
  return __builtin_isfinite(v) ? v : 0.f;
}
// [rows][128 bf16] region, 256B rows, 16B-chunk xor swizzle
__device__ __forceinline__ int swz(int row, int ch){ return (row << 8) | ((ch ^ (row & 15)) << 4); }
// [rows][256 bf16] region, 512B rows, 32 chunks; xor low4 only (bijective)
__device__ __forceinline__ int swz2(int row, int ch){ return (row << 9) | ((ch ^ (row & 15)) << 4); }
__device__ __forceinline__ floatx16 fz(){
  floatx16 z;
#pragma unroll
  for (int i = 0; i < 16; ++i) z[i] = 0.f;
  return z;
}
__device__ __forceinline__ floatx16 MF(short8 a, short8 b, floatx16 c){
  return __builtin_amdgcn_mfma_f32_32x32x16_bf16(a, b, c, 0, 0, 0);
}
// C-layout 32x32 tile (by value) -> k-chunk fragment via xor-32 exchange
// (r4-verified). cvt_pk packing + verified __shfl_xor lane exchange.
__device__ __forceinline__ short8 frag_from(floatx16 cv, int half, int q5){
  int r0 = half * 8;
  u32 e01 = pk2(cv[r0 + 0], cv[r0 + 1]);
  u32 e23 = pk2(cv[r0 + 2], cv[r0 + 3]);
  u32 o01 = pk2(cv[r0 + 4], cv[r0 + 5]);
  u32 o23 = pk2(cv[r0 + 6], cv[r0 + 7]);
  u32 s0 = q5 ? e01 : o01;
  u32 s1 = q5 ? e23 : o23;
  u32 r0v = __shfl_xor(s0, 32);
  u32 r1v = __shfl_xor(s1, 32);
  union { u32 u[4]; short8 v; } un;
  un.u[0] = q5 ? r0v : e01;
  un.u[1] = q5 ? r1v : e23;
  un.u[2] = q5 ? o01 : r0v;
  un.u[3] = q5 ? o23 : r1v;
  return un.v;
}

// ---------------- dtype detector (r4-verified) ----------------
__global__ __launch_bounds__(256) void k_detect(const u16* x, int* dflag){
  __shared__ int red[256];
  int t = threadIdx.x, cnt = 0;
  for (int i = t; i < 4096; i += 256){
    u16 v = x[2 * i];
    int e = (v >> 7) & 0xFF;
    if (e == 0xFF || e >= 0x90 || (e > 0 && e <= 0x20)) ++cnt;
  }
  red[t] = cnt;
  __syncthreads();
  for (int off = 128; off > 0; off >>= 1){
    if (t < off) red[t] += red[t + off];
    __syncthreads();
  }
  if (t == 0) dflag[0] = (red[0] > 1000) ? 1 : 0;
}

// ---------------- prep kernels ----------------

// MrowT[a][b] = M'[b,a]; vWT[d][e] = vW[e][d]; uv = u'.
__global__ __launch_bounds__(128) void k_prepw(const u16* qW, const u16* kW, const u16* vW,
                                               const u16* qb, u16* MrT, u16* vWT, float* uv,
                                               const int* dflag){
  int fl = dflag[0];
  int i = blockIdx.x >> 7, f = blockIdx.x & 127, e = threadIdx.x;
  size_t qo = (size_t)(i * 128 + e) * 128;   // qW row e
  size_t ko = (size_t)(i * 128 + f) * 128;   // kW row f
  float m = 0.f;
  for (int d = 0; d < 128; ++d) m += ldf(qW, qo + d, fl) * ldf(kW, ko + d, fl);
  const float RS = 0.08838834764831845f;  // 1/sqrt(128)
  MrT[(i * 128 + f) * 128 + e] = f2b(m * RS);                 // MrowT[f][e] = M'[e,f]
  vWT[(i * 128 + f) * 128 + e] = f2b(ldf(vW, qo + f, fl));    // vWT[d][e] = vW[e][d]
  __shared__ float red[128];
  red[e] = ldf(kW, ko + e, fl) * ldf(qb, (size_t)i * 128 + e, fl);
  __syncthreads();
  for (int off = 64; off > 0; off >>= 1){
    if (e < off) red[e] += red[e + off];
    __syncthreads();
  }
  if (e == 0) uv[i * 128 + f] = red[0] * RS;
}

__global__ __launch_bounds__(256) void k_h1t(const u16* h1W, u16* h1WT, const int* dflag){
  int fl = dflag[0];
  __shared__ u16 tile[64][130];
  int k0 = blockIdx.x * 64, tid = threadIdx.x;
#pragma unroll 4
  for (int it = 0; it < 32; ++it){
    int r = it * 2 + (tid >> 7), c = tid & 127;
    tile[r][c] = f2b(ldf(h1W, (size_t)(k0 + r) * 128 + c, fl));
  }
  __syncthreads();
#pragma unroll 4
  for (int it = 0; it < 32; ++it){
    int idx = it * 256 + tid, n = idx >> 6, kk = idx & 63;
    h1WT[(size_t)n * 32896 + k0 + kk] = tile[kk][n];
  }
}

// -------- fused embed + 2 attention layers; h in LDS; one block = one batch --------

__global__ __launch_bounds__(512, 2) void k_fan(
    const u16* x, const u16* sW, const u16* sb, const u16* hW, const u16* hbe,
    const u16* MrT, const float* uv, const u16* vWT, const u16* vb,
    const u16* lng, const u16* lnb,
    u16* hgq, u16* se, int qoff, const int* dflag){
  __shared__ alignas(16) u16 hL[32768];    // h   [256 s][128 f], swz,  64KB
  __shared__ alignas(16) u16 vt[32768];    // vT  [128 d][256 t], swz2, 64KB
  __shared__ alignas(16) float c_all[256]; // c_t + LKOFF - 8, whole layer
  __shared__ float u_lds[128];             // u' for current layer
  int fl = dflag[0];
  int bl = blockIdx.x;
  int b = qoff + bl;
  int tid = threadIdx.x, w = tid >> 6, lane = tid & 63, l31 = lane & 31, q5 = lane >> 5;
  size_t xo = (size_t)b * 272;
  const float LKOFF = -20.72326584f;       // ln(1e-9); off-diag log-kernel value

  // scalar embedding (lanes 0..127)
  if (tid < 128){
    float acc = ldf(sb, tid, fl);
#pragma unroll
    for (int j = 0; j < 16; ++j) acc += ldf(x, xo + j, fl) * ldf(sW, (size_t)j * 128 + tid, fl);
    se[(size_t)b * 128 + tid] = f2b(acc);
  }
  // history embedding -> hL (pair-packed cvt_pk)
#pragma unroll
  for (int it = 0; it < 8; ++it){
    int c = it * 512 + tid, s = c >> 4, ch = c & 15;
    float xv = ldf(x, xo + 16 + s, fl);
    float f[8];
#pragma unroll
    for (int j = 0; j < 8; ++j)
      f[j] = xv * ldf(hW, ch * 8 + j, fl) + ldf(hbe, ch * 8 + j, fl);
    union { u32 u[4]; short8 v; } rr_;
#pragma unroll
    for (int j2 = 0; j2 < 4; ++j2) rr_.u[j2] = pk2(f[2 * j2], f[2 * j2 + 1]);
    *(short8*)((char*)hL + swz(s, ch)) = rr_.v;
  }

  int mtv = w & 3;                         // d-chunk for v producer
  int scol = 32 * w + l31;

#pragma unroll 1
  for (int li = 0; li < 2; ++li){
    const u16* Ta   = MrT + li * 16384;
    const u16* vWTi = vWT + li * 16384;
    if (tid < 128) u_lds[tid] = uv[li * 128 + tid];
    float vbl = ldf(vb, (size_t)li * 128 + 32 * mtv + l31, fl);
    __syncthreads();                 // hL (embed/prev epilogue) + u_lds visible

    // ---- qh_s = h_s.M' into registers: D[e][s] tiles, lane = col = s = scol.
    short8 qhf[8];
#pragma unroll
    for (int et = 0; et < 4; ++et){
      floatx16 qa = fz();
#pragma unroll 2
      for (int kc = 0; kc < 8; ++kc){
        short8 av = *(const short8*)(Ta + (32 * et + l31) * 128 + kc * 16 + q5 * 8);
        short8 bq = *(const short8*)((char*)hL + swz(32 * w + l31, 2 * kc + q5));
        qa = MF(av, bq, qa);
      }
      qhf[2 * et + 0] = frag_from(qa, 0, q5);   // e = 32et + 0..15
      qhf[2 * et + 1] = frag_from(qa, 1, q5);   // e = 32et + 16..31
    }

    // ---- c_all[t] = u'.h_t + (LKOFF - 8)  [softmax baseline folded in]
    {
      int row = 32 * w + l31;
      float dot = 0.f;
#pragma unroll 2
      for (int kc = 0; kc < 8; ++kc){
        int ch = 2 * kc + q5;
        short8 hv = *(const short8*)((char*)hL + swz(row, ch));
#pragma unroll
        for (int j = 0; j < 8; ++j) dot += u_lds[ch * 8 + j] * b2f(hv[j]);
      }
      dot += __shfl_xor(dot, 32);
      if (q5 == 0) c_all[row] = dot + (LKOFF - 8.f);
    }

    // ---- v producer: whole layer. vt[d][t] = sum_e h[t,e] vW[e,d] + vb[d].
    {
      const u16* Va = vWTi + (32 * mtv + l31) * 128 + q5 * 8;
#pragma unroll 1
      for (int u = 0; u < 4; ++u){
        int tc = (w >> 2) * 4 + u;
        floatx16 va = fz();
#pragma unroll 2
        for (int kc = 0; kc < 8; ++kc){
          short8 avV = *(const short8*)(Va + kc * 16);
          short8 bh  = *(const short8*)((char*)hL + swz(32 * tc + l31, 2 * kc + q5));
          va = MF(bh, avV, va);
        }
        // D[t][d]: lane = d-col, regs = t; 4 consecutive t -> one 8B chunk
#pragma unroll
        for (int qd = 0; qd < 4; ++qd){
          u32x2 pv;
          pv.x = pk2(va[4 * qd + 0] + vbl, va[4 * qd + 1] + vbl);
          pv.y = pk2(va[4 * qd + 2] + vbl, va[4 * qd + 3] + vbl);
          *(u32x2*)((char*)vt + swz2(32 * mtv + l31, 4 * tc + qd) + 8 * q5) = pv;
        }
      }
    }
    __syncthreads();               // vt + c_all complete

    float ls_a = 0.f, ls_b = 0.f;
    floatx16 oacc[4];
#pragma unroll
    for (int nt = 0; nt < 4; ++nt) oacc[nt] = fz();

    // ---- consumer: scores + exp + P@V over 8 t-subtiles; NO internal barriers
#pragma unroll 1
    for (int mt = 0; mt < 8; ++mt){
      floatx16 sa = fz();
      __builtin_amdgcn_s_setprio(1);
#pragma unroll
      for (int kc = 0; kc < 8; ++kc){
        short8 ah = *(const short8*)((char*)hL + swz(32 * mt + l31, 2 * kc + q5));
        sa = MF(ah, qhf[kc], sa);
      }
      __builtin_amdgcn_s_setprio(0);
      // softmax: v = sa + c2[tg]; diag removes the folded off-diag LKOFF.
#pragma unroll
      for (int g = 0; g < 4; ++g){
        f32x4 c4 = *(const f32x4*)&c_all[32 * mt + 8 * g + 4 * q5];
#pragma unroll
        for (int k = 0; k < 4; ++k){
          int reg = 4 * g + k;
          int tg = 32 * mt + 8 * g + 4 * q5 + k;
          float v = sa[reg] + c4[k];
          if (tg == scol) v -= LKOFF;
          v = fminf(fmaxf(v, -58.f), 42.f);
          float p = __expf(v);       // fixed-max softmax, shift folded into c2
          sa[reg] = p;
          if (reg & 1) ls_b += p; else ls_a += p;
        }
      }
      // pf frags computed BEFORE the bv loads so sa dies here (register diet)
      short8 pf0 = frag_from(sa, 0, q5);
      short8 pf1 = frag_from(sa, 1, q5);
      __builtin_amdgcn_s_setprio(1);
#pragma unroll
      for (int nt = 0; nt < 4; ++nt){
        short8 bv0 = *(const short8*)((char*)vt + swz2(32 * nt + l31, 4 * mt + 0 + q5));
        oacc[nt] = MF(pf0, bv0, oacc[nt]);
        short8 bv1 = *(const short8*)((char*)vt + swz2(32 * nt + l31, 4 * mt + 2 + q5));
        oacc[nt] = MF(pf1, bv1, oacc[nt]);
      }
      __builtin_amdgcn_s_setprio(0);
    }
    __syncthreads();                   // all hL reads done before epilogue writes

    // ---- epilogue: /l, +residual, LayerNorm, write back to hL (own rows only)
    float ls_tot = ls_a + ls_b;
    float l_run = ls_tot + __shfl_xor(ls_tot, 32);
    float linv = 1.f / l_run;
    float gv[4], bbv[4];
#pragma unroll
    for (int nt = 0; nt < 4; ++nt){
      gv[nt]  = ldf(lng, (size_t)li * 128 + 32 * nt + l31, fl);
      bbv[nt] = ldf(lnb, (size_t)li * 128 + 32 * nt + l31, fl);
    }
#pragma unroll
    for (int reg = 0; reg < 16; ++reg){
      int rr = (reg & 3) + 8 * (reg >> 2) + 4 * q5;
      int srow = 32 * w + rr;
      float lrv = __shfl(linv, rr);
      float s1 = 0.f, s2 = 0.f;
#pragma unroll
      for (int nt = 0; nt < 4; ++nt){
        int d = 32 * nt + l31;
        float res = b2f(*(const u16*)((char*)hL + swz(srow, d >> 3) + (d & 7) * 2));
        float v = oacc[nt][reg] * lrv + res;
        oacc[nt][reg] = v;
        s1 += v; s2 += v * v;
      }
#pragma unroll
      for (int off = 1; off < 32; off <<= 1){ s1 += __shfl_xor(s1, off); s2 += __shfl_xor(s2, off); }
      float mu = s1 * 0.0078125f;
      float rs = rsqrtf(fmaxf(s2 * 0.0078125f - mu * mu, 0.f) + 1e-5f);
#pragma unroll
      for (int nt = 0; nt < 4; ++nt){
        int d = 32 * nt + l31;
        float v = (oacc[nt][reg] - mu) * rs * gv[nt] + bbv[nt];
        *(u16*)((char*)hL + swz(srow, d >> 3) + (d & 7) * 2) = f2b(v);
      }
    }
    __syncthreads();                   // hL update visible before next layer / store
  }

  // final h -> global, coalesced 16B chunks
#pragma unroll
  for (int it = 0; it < 8; ++it){
    int c = it * 512 + tid, row = c >> 4, ch = c & 15;
    *(short8*)(hgq + (size_t)bl * 32768 + row * 128 + ch * 8) =
        *(const short8*)((char*)hL + swz(row, ch));
  }
}

// ---------------- MLP head ----------------

__global__ __launch_bounds__(256) void k_mlp1(const u16* se, const u16* hgq, const u16* h1WT,
                                              float* part, int qoff, int nb){
  int mb = blockIdx.x, ks = blockIdx.y;
  int tid = threadIdx.x, w = tid >> 6, lane = tid & 63, l31 = lane & 31, q5 = lane >> 5;
  int b0 = mb * 32;
  floatx16 acc = fz();
  const u16* brow = h1WT + (size_t)(32 * w + l31) * 32896;
  int br = b0 + l31;
  const u16* seb = se + (size_t)(qoff + br) * 128;
  const u16* hb = hgq + (size_t)br * 32768;
  for (int kk = 0; kk < 257; ++kk){
    int kbase = ks * 4112 + kk * 16;
    const u16* ap = (kbase < 128) ? (seb + kbase + q5 * 8) : (hb + (kbase - 128) + q5 * 8);
    short8 a = *(const short8*)ap;
    short8 bf = *(const short8*)(brow + kbase + q5 * 8);
    acc = MF(a, bf, acc);
  }
#pragma unroll
  for (int reg = 0; reg < 16; ++reg){
    int rr = (reg & 3) + 8 * (reg >> 2) + 4 * q5;
    part[(size_t)ks * nb * 128 + (size_t)(b0 + rr) * 128 + 32 * w + l31] = acc[reg];
  }
}

__global__ __launch_bounds__(256) void k_mlp1red(const float* part, const u16* h1b, float* z1q,
                                                 const int* dflag, int nb){
  int fl = dflag[0];
  int idx = blockIdx.x * 256 + threadIdx.x;    // 0..nb*128-1
  float s = ldf(h1b, idx & 127, fl);
  size_t stride = (size_t)nb * 128;
#pragma unroll
  for (int ks = 0; ks < 8; ++ks) s += part[(size_t)ks * stride + idx];
  z1q[idx] = fmaxf(s, 0.f);
}

__global__ __launch_bounds__(256) void k_mlp2(const float* z1, const u16* h2W, const u16* h2b,
                                              float* z2, const int* dflag){
  int fl = dflag[0];
  int idx = blockIdx.x * 256 + threadIdx.x;    // 0..131071
  int b = idx >> 6, j = idx & 63;
  float s = ldf(h2b, j, fl);
  const float* zr = z1 + (size_t)b * 128;
  for (int k = 0; k < 128; ++k) s += zr[k] * ldf(h2W, (size_t)k * 64 + j, fl);
  z2[idx] = fmaxf(s, 0.f);
}

__global__ __launch_bounds__(256) void k_mlp3(const float* z2, const u16* h3W, const u16* h3b,
                                              void* out, const int* dflag){
  int fl = dflag[0];
  int b = blockIdx.x * 256 + threadIdx.x;      // 0..2047
  float s = ldf(h3b, 0, fl);
  const float* zr = z2 + (size_t)b * 64;
#pragma unroll
  for (int j = 0; j < 64; ++j) s += zr[j] * ldf(h3W, j, fl);
  if (!__builtin_isfinite(s)) s = 0.f;
  if (fl) ((float*)out)[b] = s;
  else    ((u16*)out)[b] = f2b(s);
}

// ---------------- launch ----------------

extern "C" void kernel_launch(void* const* d_in, const int* in_sizes, int n_in,
                              void* d_out, int out_size, void* d_ws, size_t ws_size,
                              hipStream_t stream) {
  const u16* x   = (const u16*)d_in[0];
  const u16* sW  = (const u16*)d_in[1];
  const u16* sb  = (const u16*)d_in[2];
  const u16* hW  = (const u16*)d_in[3];
  const u16* hb  = (const u16*)d_in[4];
  const u16* qW  = (const u16*)d_in[5];
  const u16* qb  = (const u16*)d_in[6];
  const u16* kW  = (const u16*)d_in[7];
  // d_in[8] = kb : cancels in softmax, unused
  const u16* vW  = (const u16*)d_in[9];
  const u16* vb  = (const u16*)d_in[10];
  const u16* lng = (const u16*)d_in[11];
  const u16* lnb = (const u16*)d_in[12];
  const u16* h1W = (const u16*)d_in[13];
  const u16* h1b = (const u16*)d_in[14];
  const u16* h2W = (const u16*)d_in[15];
  const u16* h2b = (const u16*)d_in[16];
  const u16* h3W = (const u16*)d_in[17];
  const u16* h3b = (const u16*)d_in[18];

  // full-pass mode (r5-r8 ran this branch); quarter mode fallback.
  const int nb = (ws_size >= 153600000ull) ? 2048 : 512;
  const int nq = 2048 / nb;

  char* W = (char*)d_ws;
  size_t o = 0;
  u16*   hg    = (u16*)(W + o); o += (size_t)nb * 65536;   // nb*32768*2
  u16*   h1WT  = (u16*)(W + o); o += 8421376;
  u16*   se    = (u16*)(W + o); o += 524288;               // always full 2048x128 bf16
  u16*   MrT   = (u16*)(W + o); o += 65536;
  u16*   vWT   = (u16*)(W + o); o += 65536;
  float* uv    = (float*)(W + o); o += 1024;
  float* part  = (float*)(W + o); o += (size_t)nb * 4096;  // 8 * nb*128 * 4B
  float* z1    = (float*)(W + o); o += 1048576;            // always full
  float* z2    = (float*)(W + o); o += 524288;
  int*   dflag = (int*)(W + o);

  k_detect<<<1, 256, 0, stream>>>(x, dflag);
  k_prepw<<<256, 128, 0, stream>>>(qW, kW, vW, qb, MrT, vWT, uv, dflag);
  k_h1t<<<514, 256, 0, stream>>>(h1W, h1WT, dflag);

  for (int q = 0; q < nq; ++q){
    int qoff = q * nb;
    k_fan<<<nb, 512, 0, stream>>>(x, sW, sb, hW, hb, MrT, uv, vWT, vb,
                                  lng, lnb, hg, se, qoff, dflag);
    k_mlp1<<<dim3(nb / 32, 8), 256, 0, stream>>>(se, hg, h1WT, part, qoff, nb);
    k_mlp1red<<<nb / 2, 256, 0, stream>>>(part, h1b, z1 + (size_t)qoff * 128, dflag, nb);
  }

  k_mlp2<<<512, 256, 0, stream>>>(z1, h2W, h2b, z2, dflag);
  k_mlp3<<<8, 256, 0, stream>>>(z2, h3W, h3b, d_out, dflag);
}